// Round 1
// baseline (421.451 us; speedup 1.0000x reference)
//
#include <hip/hip_runtime.h>

typedef unsigned short u16;
typedef unsigned int u32;
typedef float f32x4 __attribute__((ext_vector_type(4)));
typedef __bf16 bf16x8 __attribute__((ext_vector_type(8)));

#define LAMBDA_INIT_F 0.7836057665316245f
#define ONE_MINUS_LI  0.2163942334683755f

__device__ __forceinline__ u16 f2b(float f) {
  union { float f; u32 u; } x; x.f = f;
  u32 r = x.u + 0x7fffu + ((x.u >> 16) & 1u);
  return (u16)(r >> 16);
}

__device__ __forceinline__ f32x4 mfma16(bf16x8 a, bf16x8 b, f32x4 c) {
  return __builtin_amdgcn_mfma_f32_16x16x32_bf16(a, b, c, 0, 0, 0);
}

// ---------------- elementwise cast f32 -> bf16, 8 elems/thread ----------------
__global__ __launch_bounds__(256) void cast_kernel(const float* __restrict__ in,
                                                   u16* __restrict__ out, int n8) {
  int i = blockIdx.x * 256 + threadIdx.x;
  if (i >= n8) return;
  const f32x4* p = (const f32x4*)(in + (size_t)i * 8);
  f32x4 a = p[0], b = p[1];
  union { u16 u[8]; f32x4 v; } o;
#pragma unroll
  for (int j = 0; j < 4; ++j) { o.u[j] = f2b(a[j]); o.u[4 + j] = f2b(b[j]); }
  *(f32x4*)(out + (size_t)i * 8) = o.v;
}

// ------------- tiled transpose+cast: in f32 [R][C] -> out bf16 [C][R] ---------
__global__ __launch_bounds__(256) void transpose_cast_kernel(const float* __restrict__ in,
                                                             u16* __restrict__ out,
                                                             int R, int C) {
  __shared__ float tile[32][33];
  int bx = blockIdx.x * 32;  // col base
  int by = blockIdx.y * 32;  // row base
  int tx = threadIdx.x & 31, ty = threadIdx.x >> 5;
#pragma unroll
  for (int i = 0; i < 32; i += 8)
    tile[ty + i][tx] = in[(size_t)(by + ty + i) * C + bx + tx];
  __syncthreads();
#pragma unroll
  for (int i = 0; i < 32; i += 8)
    out[(size_t)(bx + ty + i) * R + by + tx] = f2b(tile[tx][ty + i]);
}

// ---------------- RoPE (interleaved) + scale, f32 [T][Hh*64] -> bf16 [Hh][T][64]
__global__ __launch_bounds__(256) void rope_kernel(const float* __restrict__ in,
                                                   u16* __restrict__ out,
                                                   int Hh, int hshift, float scale) {
  int idx = blockIdx.x * 256 + threadIdx.x;
  int j = idx & 31;
  int hh = (idx >> 5) & (Hh - 1);
  int t = idx >> (5 + hshift);
  const float* src = in + (size_t)t * (Hh * 64) + hh * 64 + 2 * j;
  float x1 = src[0], x2 = src[1];
  float theta = (float)j * (1.0f / 32.0f);
  float denom = expf(theta * 9.210340371976184f);  // 10000^theta
  float invf = 1.0f / (denom + 1e-8f);
  float ang = (float)t * invf;
  float s = sinf(ang), c = cosf(ang);
  float o1 = (x1 * c - x2 * s) * scale;
  float o2 = (x1 * s + x2 * c) * scale;
  u32 pk = (u32)f2b(o1) | ((u32)f2b(o2) << 16);
  *(u32*)(out + ((size_t)hh * 2048 + t) * 64 + 2 * j) = pk;
}

// ---------------- GEMM: C[M][N] f32 = A[M][K] bf16 * Bt[N][K] bf16 ------------
#define BM 128
#define BN 128
#define BK 32
__global__ __launch_bounds__(256) void gemm_bt_kernel(const u16* __restrict__ A,
                                                      const u16* __restrict__ Bt,
                                                      float* __restrict__ C,
                                                      int N, int K) {
  __shared__ u16 As[BM][BK];
  __shared__ u16 Bs[BN][BK];
  const int tid = threadIdx.x;
  const int lane = tid & 63;
  const int wave = tid >> 6;
  const int m0 = blockIdx.y * BM;
  const int n0 = blockIdx.x * BN;
  const int wm = (wave >> 1) * 64;
  const int wn = (wave & 1) * 64;
  const int g = lane >> 4, c = lane & 15;
  const int srow = tid >> 2;
  const int scol = (tid & 3) * 8;

  f32x4 acc[4][4];
#pragma unroll
  for (int i = 0; i < 4; ++i)
#pragma unroll
    for (int j = 0; j < 4; ++j) acc[i][j] = (f32x4){0.f, 0.f, 0.f, 0.f};

  for (int k0 = 0; k0 < K; k0 += BK) {
#pragma unroll
    for (int it = 0; it < 2; ++it) {
      int r = srow + it * 64;
      *(f32x4*)&As[r][scol] = *(const f32x4*)(A + (size_t)(m0 + r) * K + k0 + scol);
      *(f32x4*)&Bs[r][scol] = *(const f32x4*)(Bt + (size_t)(n0 + r) * K + k0 + scol);
    }
    __syncthreads();
    bf16x8 af[4], bfr[4];
#pragma unroll
    for (int i = 0; i < 4; ++i) af[i] = *(const bf16x8*)&As[wm + i * 16 + c][g * 8];
#pragma unroll
    for (int j = 0; j < 4; ++j) bfr[j] = *(const bf16x8*)&Bs[wn + j * 16 + c][g * 8];
#pragma unroll
    for (int i = 0; i < 4; ++i)
#pragma unroll
      for (int j = 0; j < 4; ++j) acc[i][j] = mfma16(af[i], bfr[j], acc[i][j]);
    __syncthreads();
  }
#pragma unroll
  for (int i = 0; i < 4; ++i)
#pragma unroll
    for (int j = 0; j < 4; ++j) {
      int mrow = m0 + wm + i * 16 + g * 4;
      int ncol = n0 + wn + j * 16 + c;
#pragma unroll
      for (int r = 0; r < 4; ++r) C[(size_t)(mrow + r) * N + ncol] = acc[i][j][r];
    }
}

// ---------------- fused differential flash attention --------------------------
// grid: 16 heads * 32, block 256 (4 waves); wave = 16 q rows.
// Qb bf16 [32][2048][64] (pre-scaled), Kb bf16 [16][2048][64], Vt bf16 [1024][2048]
// AO bf16 [2048][2048]  row t, col h*128+dv
__global__ __launch_bounds__(256) void attn_kernel(const u16* __restrict__ Qb,
                                                   const u16* __restrict__ Kb,
                                                   const u16* __restrict__ Vt,
                                                   u16* __restrict__ AO,
                                                   const float* __restrict__ lq1,
                                                   const float* __restrict__ lk1,
                                                   const float* __restrict__ lq2,
                                                   const float* __restrict__ lk2,
                                                   const float* __restrict__ subln) {
  const int b = blockIdx.x;
  const int h = b >> 5;
  const int wave = threadIdx.x >> 6;
  const int t0 = ((b & 31) * 4 + wave) * 16;
  const int lane = threadIdx.x & 63;
  const int g = lane >> 4, c = lane & 15;

  float l1 = 0.f, l2 = 0.f;
  for (int i = 0; i < 64; ++i) { l1 += lq1[i] * lk1[i]; l2 += lq2[i] * lk2[i]; }
  const float lambda_full = expf(l1) - expf(l2) + LAMBDA_INIT_F;

  __shared__ u16 Pl[4][2][16][32];

  bf16x8 qf[2][2];
#pragma unroll
  for (int e = 0; e < 2; ++e)
#pragma unroll
    for (int d = 0; d < 2; ++d)
      qf[e][d] = *(const bf16x8*)(Qb + ((size_t)(2 * h + e) * 2048 + t0 + c) * 64 + d * 32 + g * 8);

  const u16* Kh = Kb + (size_t)h * 2048 * 64;
  const u16* Vh = Vt + (size_t)(h >> 1) * 128 * 2048;

  f32x4 O[2][8];
#pragma unroll
  for (int e = 0; e < 2; ++e)
#pragma unroll
    for (int f = 0; f < 8; ++f) O[e][f] = (f32x4){0.f, 0.f, 0.f, 0.f};
  float m[2][4], ls[2][4];
#pragma unroll
  for (int e = 0; e < 2; ++e)
#pragma unroll
    for (int r = 0; r < 4; ++r) { m[e][r] = -1e30f; ls[e][r] = 0.f; }

  for (int s0 = 0; s0 < 2048; s0 += 32) {
    bf16x8 kf[2][2];
#pragma unroll
    for (int sf = 0; sf < 2; ++sf)
#pragma unroll
      for (int d = 0; d < 2; ++d)
        kf[sf][d] = *(const bf16x8*)(Kh + (size_t)(s0 + sf * 16 + c) * 64 + d * 32 + g * 8);
    bf16x8 vf[8];
#pragma unroll
    for (int f = 0; f < 8; ++f)
      vf[f] = *(const bf16x8*)(Vh + (size_t)(f * 16 + c) * 2048 + s0 + g * 8);

#pragma unroll
    for (int e = 0; e < 2; ++e) {
      f32x4 sa[2] = {{0.f, 0.f, 0.f, 0.f}, {0.f, 0.f, 0.f, 0.f}};
#pragma unroll
      for (int sf = 0; sf < 2; ++sf) {
        sa[sf] = mfma16(qf[e][0], kf[sf][0], sa[sf]);
        sa[sf] = mfma16(qf[e][1], kf[sf][1], sa[sf]);
      }
      float mx[4];
#pragma unroll
      for (int r = 0; r < 4; ++r) mx[r] = fmaxf(sa[0][r], sa[1][r]);
#pragma unroll
      for (int off = 1; off < 16; off <<= 1)
#pragma unroll
        for (int r = 0; r < 4; ++r) mx[r] = fmaxf(mx[r], __shfl_xor(mx[r], off));
      bool need = false;
#pragma unroll
      for (int r = 0; r < 4; ++r) need = need || (mx[r] > m[e][r] + 8.f);
      if (__any(need)) {
        float sc[4];
#pragma unroll
        for (int r = 0; r < 4; ++r) {
          float mn = fmaxf(m[e][r], mx[r]);
          sc[r] = __expf(m[e][r] - mn);
          m[e][r] = mn;
        }
#pragma unroll
        for (int f = 0; f < 8; ++f)
#pragma unroll
          for (int r = 0; r < 4; ++r) O[e][f][r] *= sc[r];
#pragma unroll
        for (int r = 0; r < 4; ++r) ls[e][r] *= sc[r];
      }
      float p[2][4];
      float rs[4] = {0.f, 0.f, 0.f, 0.f};
#pragma unroll
      for (int sf = 0; sf < 2; ++sf)
#pragma unroll
        for (int r = 0; r < 4; ++r) {
          p[sf][r] = __expf(sa[sf][r] - m[e][r]);
          rs[r] += p[sf][r];
        }
#pragma unroll
      for (int off = 1; off < 16; off <<= 1)
#pragma unroll
        for (int r = 0; r < 4; ++r) rs[r] += __shfl_xor(rs[r], off);
#pragma unroll
      for (int r = 0; r < 4; ++r) ls[e][r] += rs[r];
#pragma unroll
      for (int sf = 0; sf < 2; ++sf)
#pragma unroll
        for (int r = 0; r < 4; ++r) Pl[wave][e][g * 4 + r][sf * 16 + c] = f2b(p[sf][r]);
    }
    asm volatile("s_waitcnt lgkmcnt(0)" ::: "memory");
    __builtin_amdgcn_sched_barrier(0);
#pragma unroll
    for (int e = 0; e < 2; ++e) {
      bf16x8 pa = *(const bf16x8*)&Pl[wave][e][c][g * 8];
#pragma unroll
      for (int f = 0; f < 8; ++f) O[e][f] = mfma16(pa, vf[f], O[e][f]);
    }
  }

  float inv0[4], inv1[4];
#pragma unroll
  for (int r = 0; r < 4; ++r) { inv0[r] = 1.f / ls[0][r]; inv1[r] = 1.f / ls[1][r]; }
  float res[8][4];
  float ss[4] = {0.f, 0.f, 0.f, 0.f};
#pragma unroll
  for (int f = 0; f < 8; ++f)
#pragma unroll
    for (int r = 0; r < 4; ++r) {
      float vv = O[0][f][r] * inv0[r] - lambda_full * (O[1][f][r] * inv1[r]);
      res[f][r] = vv;
      ss[r] += vv * vv;
    }
#pragma unroll
  for (int off = 1; off < 16; off <<= 1)
#pragma unroll
    for (int r = 0; r < 4; ++r) ss[r] += __shfl_xor(ss[r], off);
  float rms[4];
#pragma unroll
  for (int r = 0; r < 4; ++r)
    rms[r] = rsqrtf(ss[r] * (1.0f / 128.0f) + 1e-5f) * ONE_MINUS_LI;
  float w[8];
#pragma unroll
  for (int f = 0; f < 8; ++f) w[f] = subln[f * 16 + c];
#pragma unroll
  for (int f = 0; f < 8; ++f)
#pragma unroll
    for (int r = 0; r < 4; ++r)
      AO[(size_t)(t0 + g * 4 + r) * 2048 + h * 128 + f * 16 + c] = f2b(res[f][r] * rms[r] * w[f]);
}

// ------------------------------------------------------------------------------
extern "C" void kernel_launch(void* const* d_in, const int* in_sizes, int n_in,
                              void* d_out, int out_size, void* d_ws, size_t ws_size,
                              hipStream_t stream) {
  const float* q     = (const float*)d_in[0];
  const float* k     = (const float*)d_in[1];
  const float* v     = (const float*)d_in[2];
  const float* Wq    = (const float*)d_in[3];
  const float* Wk    = (const float*)d_in[4];
  const float* Wv    = (const float*)d_in[5];
  const float* Wout  = (const float*)d_in[6];
  const float* lq1   = (const float*)d_in[7];
  const float* lk1   = (const float*)d_in[8];
  const float* lq2   = (const float*)d_in[9];
  const float* lk2   = (const float*)d_in[10];
  const float* subln = (const float*)d_in[11];
  float* out = (float*)d_out;

  char* ws = (char*)d_ws;
  size_t off = 0;
  auto alloc = [&](size_t bytes) -> void* {
    void* p = ws + off;
    off += (bytes + 255) & ~(size_t)255;
    return p;
  };
  u16* qb  = (u16*)alloc(2048ull * 2048 * 2);
  u16* kb  = (u16*)alloc(2048ull * 2048 * 2);
  u16* vb  = (u16*)alloc(2048ull * 2048 * 2);
  u16* WqT = (u16*)alloc(2048ull * 2048 * 2);
  u16* WkT = (u16*)alloc(1024ull * 2048 * 2);
  u16* WvT = (u16*)alloc(1024ull * 2048 * 2);
  u16* WoT = (u16*)alloc(2048ull * 2048 * 2);
  float* QP = (float*)alloc(2048ull * 2048 * 4);
  float* KP = (float*)alloc(2048ull * 1024 * 4);
  float* VP = (float*)alloc(2048ull * 1024 * 4);
  u16* Qh  = (u16*)alloc(32ull * 2048 * 64 * 2);
  u16* Kh  = (u16*)alloc(16ull * 2048 * 64 * 2);
  u16* Vt  = (u16*)alloc(1024ull * 2048 * 2);
  u16* AO  = (u16*)QP;  // alias: QP dead after rope, AO written later

  // 1. cast inputs to bf16
  cast_kernel<<<2048, 256, 0, stream>>>(q, qb, 2048 * 2048 / 8);
  cast_kernel<<<2048, 256, 0, stream>>>(k, kb, 2048 * 2048 / 8);
  cast_kernel<<<2048, 256, 0, stream>>>(v, vb, 2048 * 2048 / 8);
  // 2. transpose+cast weights -> [N][K] bf16
  transpose_cast_kernel<<<dim3(64, 64), 256, 0, stream>>>(Wq, WqT, 2048, 2048);
  transpose_cast_kernel<<<dim3(32, 64), 256, 0, stream>>>(Wk, WkT, 2048, 1024);
  transpose_cast_kernel<<<dim3(32, 64), 256, 0, stream>>>(Wv, WvT, 2048, 1024);
  transpose_cast_kernel<<<dim3(64, 64), 256, 0, stream>>>(Wout, WoT, 2048, 2048);
  // 3. projections
  gemm_bt_kernel<<<dim3(16, 16), 256, 0, stream>>>(qb, WqT, QP, 2048, 2048);
  gemm_bt_kernel<<<dim3(8, 16), 256, 0, stream>>>(kb, WkT, KP, 1024, 2048);
  gemm_bt_kernel<<<dim3(8, 16), 256, 0, stream>>>(vb, WvT, VP, 1024, 2048);
  // 4. RoPE -> head-major bf16 (Q pre-scaled by 1/8)
  rope_kernel<<<(2048 * 32 * 32) / 256, 256, 0, stream>>>(QP, Qh, 32, 5, 0.125f);
  rope_kernel<<<(2048 * 16 * 32) / 256, 256, 0, stream>>>(KP, Kh, 16, 4, 1.0f);
  // 5. V transpose: VP [2048][1024] -> Vt [1024][2048]
  transpose_cast_kernel<<<dim3(32, 64), 256, 0, stream>>>(VP, Vt, 2048, 1024);
  // 6. differential flash attention -> AO bf16 [2048][2048]
  attn_kernel<<<512, 256, 0, stream>>>(Qh, Kh, Vt, AO, lq1, lk1, lq2, lk2, subln);
  // 7. output projection -> f32 d_out
  gemm_bt_kernel<<<dim3(16, 16), 256, 0, stream>>>(AO, WoT, out, 2048, 2048);
}

// Round 2
// 206.729 us; speedup vs baseline: 2.0387x; 2.0387x over previous
//
#include <hip/hip_runtime.h>

typedef unsigned short u16;
typedef unsigned int u32;
typedef float f32x4 __attribute__((ext_vector_type(4)));
typedef __bf16 bf16x8 __attribute__((ext_vector_type(8)));
typedef __bf16 bf16x4 __attribute__((ext_vector_type(4)));

#define LAMBDA_INIT_F 0.7836057665316245f
#define ONE_MINUS_LI  0.2163942334683755f
#define THR_LOG2 11.0f
// 0.125 * log2(e): fold softmax base-2 conversion into Q scaling
#define Q_SCALE 0.18033688011112042f

__device__ __forceinline__ u16 f2b(float f) {
  union { float f; u32 u; } x; x.f = f;
  u32 r = x.u + 0x7fffu + ((x.u >> 16) & 1u);
  return (u16)(r >> 16);
}

__device__ __forceinline__ f32x4 mfma16(bf16x8 a, bf16x8 b, f32x4 c) {
  return __builtin_amdgcn_mfma_f32_16x16x32_bf16(a, b, c, 0, 0, 0);
}

// async global->LDS, 16B per lane; LDS dest must be linear in lane order
__device__ __forceinline__ void gll16(const void* gp, void* lp) {
  __builtin_amdgcn_global_load_lds((__attribute__((address_space(1))) void*)(gp),
                                   (__attribute__((address_space(3))) void*)(lp),
                                   16, 0, 0);
}

// ---------------- elementwise cast f32 -> bf16, 8 elems/thread ----------------
__global__ __launch_bounds__(256) void cast_kernel(const float* __restrict__ in,
                                                   u16* __restrict__ out, int n8) {
  int i = blockIdx.x * 256 + threadIdx.x;
  if (i >= n8) return;
  const f32x4* p = (const f32x4*)(in + (size_t)i * 8);
  f32x4 a = p[0], b = p[1];
  union { u16 u[8]; f32x4 v; } o;
#pragma unroll
  for (int j = 0; j < 4; ++j) { o.u[j] = f2b(a[j]); o.u[4 + j] = f2b(b[j]); }
  *(f32x4*)(out + (size_t)i * 8) = o.v;
}

// ------------- tiled transpose+cast: in f32 [R][C] -> out bf16 [C][R] ---------
__global__ __launch_bounds__(256) void transpose_cast_kernel(const float* __restrict__ in,
                                                             u16* __restrict__ out,
                                                             int R, int C) {
  __shared__ float tile[32][33];
  int bx = blockIdx.x * 32;  // col base
  int by = blockIdx.y * 32;  // row base
  int tx = threadIdx.x & 31, ty = threadIdx.x >> 5;
#pragma unroll
  for (int i = 0; i < 32; i += 8)
    tile[ty + i][tx] = in[(size_t)(by + ty + i) * C + bx + tx];
  __syncthreads();
#pragma unroll
  for (int i = 0; i < 32; i += 8)
    out[(size_t)(bx + ty + i) * R + by + tx] = f2b(tile[tx][ty + i]);
}

// ---------------- RoPE (interleaved) + scale, f32 [T][Hh*64] -> bf16 [Hh][T][64]
__global__ __launch_bounds__(256) void rope_kernel(const float* __restrict__ in,
                                                   u16* __restrict__ out,
                                                   int Hh, int hshift, float scale) {
  int idx = blockIdx.x * 256 + threadIdx.x;
  int j = idx & 31;
  int hh = (idx >> 5) & (Hh - 1);
  int t = idx >> (5 + hshift);
  const float* src = in + (size_t)t * (Hh * 64) + hh * 64 + 2 * j;
  float x1 = src[0], x2 = src[1];
  float theta = (float)j * (1.0f / 32.0f);
  float denom = expf(theta * 9.210340371976184f);  // 10000^theta
  float invf = 1.0f / (denom + 1e-8f);
  float ang = (float)t * invf;
  float s = sinf(ang), c = cosf(ang);
  float o1 = (x1 * c - x2 * s) * scale;
  float o2 = (x1 * s + x2 * c) * scale;
  u32 pk = (u32)f2b(o1) | ((u32)f2b(o2) << 16);
  *(u32*)(out + ((size_t)hh * 2048 + t) * 64 + 2 * j) = pk;
}

// ---------------- GEMM body: C[M][N] f32 = A[M][K] bf16 * Bt[N][K] bf16 -------
// m97 structure: 128x128 tile, BK=64, global_load_lds w=16, granule-XOR swizzle
__device__ __forceinline__ void gemm_body(u16* As, u16* Bs,
                                          const u16* __restrict__ A,
                                          const u16* __restrict__ Bt,
                                          float* __restrict__ C,
                                          int N, int K, int bx, int by) {
  const int tid = threadIdx.x;
  const int lane = tid & 63;
  const int wave = tid >> 6;
  const int m0 = by * 128;
  const int n0 = bx * 128;
  const int wm = (wave >> 1) * 64;
  const int wn = (wave & 1) * 64;
  const int g = lane >> 4, c = lane & 15;

  f32x4 acc[4][4];
#pragma unroll
  for (int i = 0; i < 4; ++i)
#pragma unroll
    for (int j = 0; j < 4; ++j) acc[i][j] = (f32x4){0.f, 0.f, 0.f, 0.f};

  for (int k0 = 0; k0 < K; k0 += 64) {
    __syncthreads();  // previous tile fully consumed before overwrite
#pragma unroll
    for (int it = 0; it < 4; ++it) {
      int gi = it * 256 + tid;
      int R = gi >> 3;                    // tile row
      int lg = (gi & 7) ^ (R & 7);        // inverse-swizzled source granule
      gll16(A + (size_t)(m0 + R) * K + k0 + lg * 8, As + gi * 8);
      gll16(Bt + (size_t)(n0 + R) * K + k0 + lg * 8, Bs + gi * 8);
    }
    __syncthreads();  // implies vmcnt(0): staged data visible
#pragma unroll
    for (int kk = 0; kk < 2; ++kk) {
      bf16x8 af[4], bf[4];
#pragma unroll
      for (int i = 0; i < 4; ++i) {
        int ph = ((kk * 4 + g) ^ (c & 7)) * 8;
        af[i] = *(const bf16x8*)&As[(wm + i * 16 + c) * 64 + ph];
        bf[i] = *(const bf16x8*)&Bs[(wn + i * 16 + c) * 64 + ph];
      }
#pragma unroll
      for (int i = 0; i < 4; ++i)
#pragma unroll
        for (int j = 0; j < 4; ++j) acc[i][j] = mfma16(af[i], bf[j], acc[i][j]);
    }
  }
#pragma unroll
  for (int i = 0; i < 4; ++i)
#pragma unroll
    for (int j = 0; j < 4; ++j) {
      int mrow = m0 + wm + i * 16 + g * 4;
      int ncol = n0 + wn + j * 16 + c;
#pragma unroll
      for (int r = 0; r < 4; ++r) C[(size_t)(mrow + r) * N + ncol] = acc[i][j][r];
    }
}

// fused q/k/v projections in one launch: 256 + 128 + 128 = 512 blocks (2/CU)
__global__ __launch_bounds__(256, 2) void gemm_qkv_kernel(
    const u16* __restrict__ qb, const u16* __restrict__ WqT, float* __restrict__ QP,
    const u16* __restrict__ kb, const u16* __restrict__ WkT, float* __restrict__ KP,
    const u16* __restrict__ vb, const u16* __restrict__ WvT, float* __restrict__ VP) {
  __shared__ u16 As[128 * 64];
  __shared__ u16 Bs[128 * 64];
  int bid = blockIdx.x;
  if (bid < 256) {
    gemm_body(As, Bs, qb, WqT, QP, 2048, 2048, bid & 15, bid >> 4);
  } else if (bid < 384) {
    int t = bid - 256;
    gemm_body(As, Bs, kb, WkT, KP, 1024, 2048, t & 7, t >> 3);
  } else {
    int t = bid - 384;
    gemm_body(As, Bs, vb, WvT, VP, 1024, 2048, t & 7, t >> 3);
  }
}

__global__ __launch_bounds__(256, 2) void gemm_one_kernel(const u16* __restrict__ A,
                                                          const u16* __restrict__ Bt,
                                                          float* __restrict__ C) {
  __shared__ u16 As[128 * 64];
  __shared__ u16 Bs[128 * 64];
  gemm_body(As, Bs, A, Bt, C, 2048, 2048, blockIdx.x & 15, blockIdx.x >> 4);
}

// ---------------- fused differential flash attention --------------------------
// Swapped-QK orientation: sa = mfma(K, Q) -> lane holds scores for ONE q-row
// (col=lane&15=q-row), keys in regs. K/V tiles double-buffered in LDS via
// global_load_lds with granule-XOR swizzle (pre-swizzled global source).
// grid: 16 heads * 32 qblocks, block 256 (4 waves x 16 q-rows).
__global__ __launch_bounds__(256, 2) void attn_kernel(const u16* __restrict__ Qb,
                                                      const u16* __restrict__ Kb,
                                                      const u16* __restrict__ Vt,
                                                      u16* __restrict__ AO,
                                                      const float* __restrict__ lq1,
                                                      const float* __restrict__ lk1,
                                                      const float* __restrict__ lq2,
                                                      const float* __restrict__ lk2,
                                                      const float* __restrict__ subln) {
  const int b = blockIdx.x;
  const int h = b >> 5;
  const int tid = threadIdx.x;
  const int wave = tid >> 6;
  const int lane = tid & 63;
  const int t0 = ((b & 31) * 4 + wave) * 16;
  const int g = lane >> 4, c = lane & 15;

  __shared__ u16 Ks[2][64 * 64];    // [buf][key][d]   8KB each
  __shared__ u16 Vs[2][128 * 64];   // [buf][dv][key] 16KB each
  __shared__ u16 Ps[4][2][16 * 64]; // [wave][e][qrow][key] 2KB each

  const u16* Kh = Kb + (size_t)h * 2048 * 64;
  const u16* Vh = Vt + (size_t)(h >> 1) * 128 * 2048;

  // lambda (wave-parallel)
  float myl1 = lq1[lane] * lk1[lane];
  float myl2 = lq2[lane] * lk2[lane];
#pragma unroll
  for (int off = 32; off; off >>= 1) {
    myl1 += __shfl_xor(myl1, off);
    myl2 += __shfl_xor(myl2, off);
  }
  const float lambda_full = expf(myl1) - expf(myl2) + LAMBDA_INIT_F;

  // Q fragments (B-operand: col = q-row = lane&15)
  bf16x8 qf[2][2];
#pragma unroll
  for (int e = 0; e < 2; ++e)
#pragma unroll
    for (int d = 0; d < 2; ++d)
      qf[e][d] = *(const bf16x8*)(Qb + ((size_t)(2 * h + e) * 2048 + t0 + c) * 64 + d * 32 + g * 8);

  f32x4 O[2][8];
#pragma unroll
  for (int e = 0; e < 2; ++e)
#pragma unroll
    for (int f = 0; f < 8; ++f) O[e][f] = (f32x4){0.f, 0.f, 0.f, 0.f};
  float m0 = -1e30f, m1 = -1e30f, ls0 = 0.f, ls1 = 0.f;

  // stage K (512 granules) + V (1024 granules) into buf, pre-swizzled source
#define STAGE(buf, s0)                                                        \
  {                                                                           \
    _Pragma("unroll") for (int it = 0; it < 2; ++it) {                        \
      int gi = it * 256 + tid;                                                \
      int R = gi >> 3;                                                        \
      int lg = (gi & 7) ^ (R & 7);                                            \
      gll16(Kh + (size_t)((s0) + R) * 64 + lg * 8, &Ks[buf][gi * 8]);         \
    }                                                                         \
    _Pragma("unroll") for (int it = 0; it < 4; ++it) {                        \
      int gi = it * 256 + tid;                                                \
      int R = gi >> 3;                                                        \
      int lg = (gi & 7) ^ (R & 7);                                            \
      gll16(Vh + (size_t)R * 2048 + (s0) + lg * 8, &Vs[buf][gi * 8]);         \
    }                                                                         \
  }

  STAGE(0, 0);

  for (int t = 0; t < 32; ++t) {
    const int cur = t & 1;
    __syncthreads();  // drains vmcnt: buf `cur` staged & everyone done with cur^1
    if (t < 31) STAGE(cur ^ 1, (t + 1) * 64);

    const u16* K0 = Ks[cur];
    const u16* V0 = Vs[cur];

    // K fragments (A-operand: row = key), shared across both sub-heads
    bf16x8 kf[4][2];
#pragma unroll
    for (int sf = 0; sf < 4; ++sf)
#pragma unroll
      for (int d = 0; d < 2; ++d) {
        int ph = ((d * 4 + g) ^ (c & 7)) * 8;
        kf[sf][d] = *(const bf16x8*)&K0[(sf * 16 + c) * 64 + ph];
      }

#pragma unroll
    for (int e = 0; e < 2; ++e) {
      f32x4 sa[4];
#pragma unroll
      for (int sf = 0; sf < 4; ++sf) {
        sa[sf] = (f32x4){0.f, 0.f, 0.f, 0.f};
        sa[sf] = mfma16(kf[sf][0], qf[e][0], sa[sf]);
        sa[sf] = mfma16(kf[sf][1], qf[e][1], sa[sf]);
      }
      // lane-local row max over 16 scores + 2 shfl across g-groups
      float mx = sa[0][0];
#pragma unroll
      for (int sf = 0; sf < 4; ++sf)
#pragma unroll
        for (int r = 0; r < 4; ++r) mx = fmaxf(mx, sa[sf][r]);
      mx = fmaxf(mx, __shfl_xor(mx, 16));
      mx = fmaxf(mx, __shfl_xor(mx, 32));

      float& m_e = e ? m1 : m0;
      float& ls_e = e ? ls1 : ls0;
      if (__any(mx > m_e + THR_LOG2)) {
        float mn = fmaxf(m_e, mx);
        float sc = exp2f(m_e - mn);
        m_e = mn;
        ls_e *= sc;
        float scr[4];
#pragma unroll
        for (int r = 0; r < 4; ++r) scr[r] = __shfl(sc, g * 4 + r);
#pragma unroll
        for (int f = 0; f < 8; ++f)
#pragma unroll
          for (int r = 0; r < 4; ++r) O[e][f][r] *= scr[r];
      }
      float sum = 0.f;
#pragma unroll
      for (int sf = 0; sf < 4; ++sf) {
        float p0 = exp2f(sa[sf][0] - m_e);
        float p1 = exp2f(sa[sf][1] - m_e);
        float p2 = exp2f(sa[sf][2] - m_e);
        float p3 = exp2f(sa[sf][3] - m_e);
        sum += (p0 + p1) + (p2 + p3);
        bf16x4 pk = {(__bf16)p0, (__bf16)p1, (__bf16)p2, (__bf16)p3};
        int ph = (sf * 2 + (g >> 1)) ^ (c & 7);
        *(bf16x4*)&Ps[wave][e][c * 64 + ph * 8 + (g & 1) * 4] = pk;
      }
      sum += __shfl_xor(sum, 16);
      sum += __shfl_xor(sum, 32);
      ls_e += sum;
    }

    // PV: A = P (row = q-row), B = V^T (col = dv)
#pragma unroll
    for (int kk = 0; kk < 2; ++kk) {
      int php = ((kk * 4 + g) ^ (c & 7)) * 8;
      bf16x8 pa0 = *(const bf16x8*)&Ps[wave][0][c * 64 + php];
      bf16x8 pa1 = *(const bf16x8*)&Ps[wave][1][c * 64 + php];
#pragma unroll
      for (int f = 0; f < 8; ++f) {
        bf16x8 vv = *(const bf16x8*)&V0[(f * 16 + c) * 64 + php];
        O[0][f] = mfma16(pa0, vv, O[0][f]);
        O[1][f] = mfma16(pa1, vv, O[1][f]);
      }
    }
  }

  // epilogue: redistribute 1/ls from c-layout to (g,r)-layout
  float inv0 = 1.f / ls0, inv1 = 1.f / ls1;
  float i0[4], i1[4];
#pragma unroll
  for (int r = 0; r < 4; ++r) {
    i0[r] = __shfl(inv0, g * 4 + r);
    i1[r] = __shfl(inv1, g * 4 + r);
  }
  float res[8][4];
  float ss[4] = {0.f, 0.f, 0.f, 0.f};
#pragma unroll
  for (int f = 0; f < 8; ++f)
#pragma unroll
    for (int r = 0; r < 4; ++r) {
      float vv = O[0][f][r] * i0[r] - lambda_full * (O[1][f][r] * i1[r]);
      res[f][r] = vv;
      ss[r] += vv * vv;
    }
#pragma unroll
  for (int off = 1; off < 16; off <<= 1)
#pragma unroll
    for (int r = 0; r < 4; ++r) ss[r] += __shfl_xor(ss[r], off);
  float rms[4];
#pragma unroll
  for (int r = 0; r < 4; ++r)
    rms[r] = rsqrtf(ss[r] * (1.0f / 128.0f) + 1e-5f) * ONE_MINUS_LI;
  float w[8];
#pragma unroll
  for (int f = 0; f < 8; ++f) w[f] = subln[f * 16 + c];
#pragma unroll
  for (int f = 0; f < 8; ++f)
#pragma unroll
    for (int r = 0; r < 4; ++r)
      AO[(size_t)(t0 + g * 4 + r) * 2048 + h * 128 + f * 16 + c] = f2b(res[f][r] * rms[r] * w[f]);
}

// ------------------------------------------------------------------------------
extern "C" void kernel_launch(void* const* d_in, const int* in_sizes, int n_in,
                              void* d_out, int out_size, void* d_ws, size_t ws_size,
                              hipStream_t stream) {
  const float* q     = (const float*)d_in[0];
  const float* k     = (const float*)d_in[1];
  const float* v     = (const float*)d_in[2];
  const float* Wq    = (const float*)d_in[3];
  const float* Wk    = (const float*)d_in[4];
  const float* Wv    = (const float*)d_in[5];
  const float* Wout  = (const float*)d_in[6];
  const float* lq1   = (const float*)d_in[7];
  const float* lk1   = (const float*)d_in[8];
  const float* lq2   = (const float*)d_in[9];
  const float* lk2   = (const float*)d_in[10];
  const float* subln = (const float*)d_in[11];
  float* out = (float*)d_out;

  char* ws = (char*)d_ws;
  size_t off = 0;
  auto alloc = [&](size_t bytes) -> void* {
    void* p = ws + off;
    off += (bytes + 255) & ~(size_t)255;
    return p;
  };
  u16* qb  = (u16*)alloc(2048ull * 2048 * 2);
  u16* kb  = (u16*)alloc(2048ull * 2048 * 2);
  u16* vb  = (u16*)alloc(2048ull * 2048 * 2);
  u16* WqT = (u16*)alloc(2048ull * 2048 * 2);
  u16* WkT = (u16*)alloc(1024ull * 2048 * 2);
  u16* WvT = (u16*)alloc(1024ull * 2048 * 2);
  u16* WoT = (u16*)alloc(2048ull * 2048 * 2);
  float* QP = (float*)alloc(2048ull * 2048 * 4);
  float* KP = (float*)alloc(2048ull * 1024 * 4);
  float* VP = (float*)alloc(2048ull * 1024 * 4);
  u16* Qh  = (u16*)alloc(32ull * 2048 * 64 * 2);
  u16* Kh  = (u16*)alloc(16ull * 2048 * 64 * 2);
  u16* Vt  = (u16*)alloc(1024ull * 2048 * 2);
  u16* AO  = (u16*)QP;  // alias: QP dead after rope, AO written later

  // 1. cast inputs to bf16
  cast_kernel<<<2048, 256, 0, stream>>>(q, qb, 2048 * 2048 / 8);
  cast_kernel<<<2048, 256, 0, stream>>>(k, kb, 2048 * 2048 / 8);
  cast_kernel<<<2048, 256, 0, stream>>>(v, vb, 2048 * 2048 / 8);
  // 2. transpose+cast weights -> [N][K] bf16
  transpose_cast_kernel<<<dim3(64, 64), 256, 0, stream>>>(Wq, WqT, 2048, 2048);
  transpose_cast_kernel<<<dim3(32, 64), 256, 0, stream>>>(Wk, WkT, 2048, 1024);
  transpose_cast_kernel<<<dim3(32, 64), 256, 0, stream>>>(Wv, WvT, 2048, 1024);
  transpose_cast_kernel<<<dim3(64, 64), 256, 0, stream>>>(Wout, WoT, 2048, 2048);
  // 3. projections (fused single launch, 512 blocks)
  gemm_qkv_kernel<<<512, 256, 0, stream>>>(qb, WqT, QP, kb, WkT, KP, vb, WvT, VP);
  // 4. RoPE -> head-major bf16 (Q pre-scaled by 1/8 * log2e for exp2 softmax)
  rope_kernel<<<(2048 * 32 * 32) / 256, 256, 0, stream>>>(QP, Qh, 32, 5, Q_SCALE);
  rope_kernel<<<(2048 * 16 * 32) / 256, 256, 0, stream>>>(KP, Kh, 16, 4, 1.0f);
  // 5. V transpose: VP [2048][1024] -> Vt [1024][2048]
  transpose_cast_kernel<<<dim3(32, 64), 256, 0, stream>>>(VP, Vt, 2048, 1024);
  // 6. differential flash attention -> AO bf16 [2048][2048]
  attn_kernel<<<512, 256, 0, stream>>>(Qh, Kh, Vt, AO, lq1, lk1, lq2, lk2, subln);
  // 7. output projection -> f32 d_out
  gemm_one_kernel<<<256, 256, 0, stream>>>(AO, WoT, out);
}